// Round 5
// baseline (2911.796 us; speedup 1.0000x reference)
//
#include <hip/hip_runtime.h>
#include <hip/hip_bf16.h>

// AttentiveFuturecaster: fused GRU-encoder + attentive GRU-decoder + FC head.
// Round 7 (on R6's 1890us): force the software pipeline the compiler keeps
// defeating. (a) sched_barrier(0) after every ring iteration pins loads
// against sinking (VGPR tripwire: binary must exceed 128 now); PD 6->8.
// (b) intra-loop barriers only protect LDS dataflow -> replace __syncthreads
// (which drains vmcnt(0), killing cross-step prefetch) with
// lgkmcnt(0)+s_barrier+sched_barrier(0). Weight-ring loads now stay in
// flight ACROSS the per-step barrier (T3/T4 counted-vmcnt pattern; vmcnt is
// in-order and each ring is issued in use order). One full __syncthreads()
// remains at decoder entry to drain hs stores before P2 re-reads.
// (c) decoder: f1W ring issued before the P3-end barrier; P2 issues its hs
// stream before the dWhh ring. Numerics bit-identical to R6.
// ws layout: [0, 128MB): hs bf16 [B,T,H]; then 1MB PACKED bf16 weight blob.

#define B_    2048
#define T_    128
#define F_    64
#define H_    256
#define OUT_  32
#define BT_   16
#define NTH_  512
#define NB_   (B_ / BT_)
#define PD_   8     // weight-ring pipeline depth (gate-triples)
#define HSTR_ 264   // bf16 h-tile LDS row stride
#define FSTR_ 260   // fp32 h-tile LDS row stride
#define XSTR_ 72    // bf16 x-tile LDS row stride
#define SSTR_ 260   // fp32 scratch row stride (softmax w / fc1 out)

// PACKED bf16 weight blob element offsets inside ws (after hs).
// Layout: chunks of 512 elements (1KB). eWhh/dWhh: chunk=((c*8+kk)*3+q),
// eWih: ((c*2+kk)*3+q), f1W: (c*8+kk). Within chunk: lane*8+e, where the
// fragment for lane (quad=lane>>4,l16=lane&15) is row q*H+16c+l16,
// cols kk*32+quad*8+e  — exactly the original per-lane load addresses.
#define PK_EHH_ 0
#define PK_EIH_ (PK_EHH_ + 3 * H_ * H_)    // 196608
#define PK_DHH_ (PK_EIH_ + 3 * H_ * F_)    // 245760
#define PK_F1_  (PK_DHH_ + 3 * H_ * H_)    // 442368
#define W_TOT_  (PK_F1_ + H_ * H_)         // 507904

typedef __attribute__((ext_vector_type(8))) short bf16x8;
typedef __attribute__((ext_vector_type(4))) float f32x4;

__device__ __forceinline__ f32x4 mfma16(bf16x8 a, bf16x8 b, f32x4 c) {
  return __builtin_amdgcn_mfma_f32_16x16x32_bf16(a, b, c, 0, 0, 0);
}
__device__ __forceinline__ float sigm_(float x) { return 1.0f / (1.0f + __expf(-x)); }
__device__ __forceinline__ float tanh_(float x) {
  x = fminf(15.0f, fmaxf(-15.0f, x));
  float e = __expf(2.0f * x);
  return (e - 1.0f) / (e + 1.0f);
}
// LDS-only barrier: does NOT drain vmcnt, so global (weight-ring) loads
// survive across it. sched_barrier fences both directions (rule #18).
__device__ __forceinline__ void barrier_lds() {
  __builtin_amdgcn_sched_barrier(0);
  asm volatile("s_waitcnt lgkmcnt(0)" ::: "memory");
  __builtin_amdgcn_s_barrier();
  __builtin_amdgcn_sched_barrier(0);
}

__global__ __launch_bounds__(256) void af_convert_weights(
    const float* __restrict__ eWih, const float* __restrict__ eWhh,
    const float* __restrict__ dWhh, const float* __restrict__ f1W,
    __hip_bfloat16* __restrict__ wb) {
  for (int i = blockIdx.x * blockDim.x + threadIdx.x; i < W_TOT_;
       i += gridDim.x * blockDim.x) {
    float v;
    int o, chunk, r, ln, e, q, ck, c, kk, row, col;
    if (i < PK_EIH_) {            // packed eWhh
      o = i;
      chunk = o >> 9; r = o & 511; ln = r >> 3; e = r & 7;
      q = chunk % 3; ck = chunk / 3; c = ck >> 3; kk = ck & 7;
      row = q * H_ + c * 16 + (ln & 15);
      col = kk * 32 + (ln >> 4) * 8 + e;
      v = eWhh[row * H_ + col];
    } else if (i < PK_DHH_) {     // packed eWih
      o = i - PK_EIH_;
      chunk = o >> 9; r = o & 511; ln = r >> 3; e = r & 7;
      q = chunk % 3; ck = chunk / 3; c = ck >> 1; kk = ck & 1;
      row = q * H_ + c * 16 + (ln & 15);
      col = kk * 32 + (ln >> 4) * 8 + e;
      v = eWih[row * F_ + col];
    } else if (i < PK_F1_) {      // packed dWhh
      o = i - PK_DHH_;
      chunk = o >> 9; r = o & 511; ln = r >> 3; e = r & 7;
      q = chunk % 3; ck = chunk / 3; c = ck >> 3; kk = ck & 7;
      row = q * H_ + c * 16 + (ln & 15);
      col = kk * 32 + (ln >> 4) * 8 + e;
      v = dWhh[row * H_ + col];
    } else {                      // packed f1W
      o = i - PK_F1_;
      chunk = o >> 9; r = o & 511; ln = r >> 3; e = r & 7;
      c = chunk >> 3; kk = chunk & 7;
      row = c * 16 + (ln & 15);
      col = kk * 32 + (ln >> 4) * 8 + e;
      v = f1W[row * H_ + col];
    }
    wb[i] = __float2bfloat16(v);
  }
}

__global__ __launch_bounds__(NTH_, 2) void af_fused_kernel(
    const float* __restrict__ x,
    const float* __restrict__ h0,
    const float* __restrict__ ebih,
    const float* __restrict__ ebhh,
    const float* __restrict__ dWih,
    const float* __restrict__ dbih,
    const float* __restrict__ dbhh,
    const float* __restrict__ aWq,
    const float* __restrict__ abq,
    const float* __restrict__ f1b,
    const float* __restrict__ f2W,
    const float* __restrict__ f2b,
    const __hip_bfloat16* __restrict__ eWihB,   // packed
    const __hip_bfloat16* __restrict__ eWhhB,   // packed
    const __hip_bfloat16* __restrict__ dWhhB,   // packed
    const __hip_bfloat16* __restrict__ f1WB,    // packed
    __hip_bfloat16* __restrict__ hs,     // [B,T,H] bf16 (workspace)
    float* __restrict__ dout)            // [B,OUT] fp32
{
  __shared__ __hip_bfloat16 sh_h[2][BT_ * HSTR_];   // h hi (bf16)
  __shared__ __hip_bfloat16 sh_l[2][BT_ * HSTR_];   // h lo (bf16 residual)
  __shared__ float          s_hf[2][BT_ * FSTR_];   // h fp32 (carried state)
  __shared__ __hip_bfloat16 sh_x[2][BT_ * XSTR_];   // x hi
  __shared__ __hip_bfloat16 sh_xl[2][BT_ * XSTR_];  // x lo
  __shared__ float s_A[BT_ * T_], s_C[BT_ * T_];    // rank-1 attention tables
  __shared__ float s_ebr[H_], s_ebz[H_], s_ebin[H_], s_ebhn[H_];
  __shared__ float s_dbr[H_], s_dbz[H_], s_dbin[H_], s_dbhn[H_];
  __shared__ float s_dwih[3 * H_];
  __shared__ float s_wq[H_], s_bq[H_], s_f1b[H_], s_f2w[H_];
  __shared__ float s_f2b;
  __shared__ float s_prev[BT_];
  __shared__ float s_scr[BT_ * SSTR_];  // softmax w (cols 0..127) / fc1 out (cols 0..255)

  const int tid  = threadIdx.x;
  const int b0   = blockIdx.x * BT_;
  const int lane = tid & 63;
  const int wid  = tid >> 6;     // 0..7
  const int quad = lane >> 4;    // 0..3
  const int l16  = lane & 15;    // 0..15
  const int mg   = tid >> 5;     // 0..15: batch row for 32-thread-group phases
  const int cg   = tid & 31;     // 0..31: position within group
  const int lofs = lane * 8;     // element offset within a packed 512-elem chunk

  // A-operand fragments (shared across phases) + weight register ring
  bf16x8 ah[8], al[8], ax[2], axl[2];
  bf16x8 rb[PD_], rz[PD_], rn[PD_];

  // ---- pipelined weight loaders: packed chunks, 1KB contiguous per wave ----
  auto load_enc = [&](int j) {            // j in [0,20)
    const int slot = j & 7;
    const int s2 = j < 10 ? 0 : 1;
    const int lo = j - s2 * 10;
    const int c = 2 * wid + s2;
    const __hip_bfloat16* p;
    if (lo < 8) p = eWhhB + (size_t)((c * 8 + lo) * 3) * 512 + lofs;
    else        p = eWihB + (size_t)((c * 2 + (lo - 8)) * 3) * 512 + lofs;
    rb[slot] = *(const bf16x8*)p;
    rz[slot] = *(const bf16x8*)(p + 512);
    rn[slot] = *(const bf16x8*)(p + 1024);
  };
  auto load_dec = [&](int j) {            // j in [0,16)
    const int slot = j & 7;
    const __hip_bfloat16* p =
        dWhhB + (size_t)(((2 * wid + (j >> 3)) * 8 + (j & 7)) * 3) * 512 + lofs;
    rb[slot] = *(const bf16x8*)p;
    rz[slot] = *(const bf16x8*)(p + 512);
    rn[slot] = *(const bf16x8*)(p + 1024);
  };
  auto load_fc = [&](int j) {             // j in [0,16)
    const int slot = j & 7;
    rb[slot] = *(const bf16x8*)(
        f1WB + (size_t)((2 * wid + (j >> 3)) * 8 + (j & 7)) * 512 + lofs);
  };
  // ---- consumers (lo-split MFMA, order identical to round-2) ----
  auto use_whh = [&](int kk, int slot, f32x4& ar, f32x4& az, f32x4& anh) {
    ar  = mfma16(al[kk], rb[slot], ar);  ar  = mfma16(ah[kk], rb[slot], ar);
    az  = mfma16(al[kk], rz[slot], az);  az  = mfma16(ah[kk], rz[slot], az);
    anh = mfma16(al[kk], rn[slot], anh); anh = mfma16(ah[kk], rn[slot], anh);
  };
  auto use_wih = [&](int kk, int slot, f32x4& ar, f32x4& az, f32x4& ani) {
    ar  = mfma16(axl[kk], rb[slot], ar);  ar  = mfma16(ax[kk], rb[slot], ar);
    az  = mfma16(axl[kk], rz[slot], az);  az  = mfma16(ax[kk], rz[slot], az);
    ani = mfma16(axl[kk], rn[slot], ani); ani = mfma16(ax[kk], rn[slot], ani);
  };
  auto use_fc = [&](int kk, int slot, f32x4& a1) {
    a1 = mfma16(al[kk], rb[slot], a1);
    a1 = mfma16(ah[kk], rb[slot], a1);
  };

  // ---------------- prologue: constants + h0 + x(t=0) into LDS ----------------
  for (int g = tid; g < H_; g += NTH_) {
    s_ebr[g]  = ebih[g]          + ebhh[g];
    s_ebz[g]  = ebih[H_ + g]     + ebhh[H_ + g];
    s_ebin[g] = ebih[2 * H_ + g];
    s_ebhn[g] = ebhh[2 * H_ + g];
    s_dbr[g]  = dbih[g]          + dbhh[g];
    s_dbz[g]  = dbih[H_ + g]     + dbhh[H_ + g];
    s_dbin[g] = dbih[2 * H_ + g];
    s_dbhn[g] = dbhh[2 * H_ + g];
    s_wq[g]   = aWq[g];
    s_bq[g]   = abq[g];
    s_f1b[g]  = f1b[g];
    s_f2w[g]  = f2W[g];
  }
  for (int g = tid; g < 3 * H_; g += NTH_) s_dwih[g] = dWih[g];
  if (tid == 0) s_f2b = f2b[0];

  {
    const float* hp = h0 + (size_t)(b0 + mg) * H_ + cg * 8;
    float4 v0 = *(const float4*)(hp);
    float4 v1 = *(const float4*)(hp + 4);
    float vv[8] = {v0.x, v0.y, v0.z, v0.w, v1.x, v1.y, v1.z, v1.w};
#pragma unroll
    for (int j = 0; j < 8; ++j) {
      float v = vv[j];
      s_hf[0][mg * FSTR_ + cg * 8 + j] = v;
      __hip_bfloat16 hi = __float2bfloat16(v);
      sh_h[0][mg * HSTR_ + cg * 8 + j] = hi;
      sh_l[0][mg * HSTR_ + cg * 8 + j] = __float2bfloat16(v - __bfloat162float(hi));
    }
    float2 xv = *(const float2*)(x + ((size_t)(b0 + mg) * T_) * F_ + cg * 2);
    __hip_bfloat16 xh0 = __float2bfloat16(xv.x);
    __hip_bfloat16 xh1 = __float2bfloat16(xv.y);
    sh_x[0][mg * XSTR_ + cg * 2]      = xh0;
    sh_x[0][mg * XSTR_ + cg * 2 + 1]  = xh1;
    sh_xl[0][mg * XSTR_ + cg * 2]     = __float2bfloat16(xv.x - __bfloat162float(xh0));
    sh_xl[0][mg * XSTR_ + cg * 2 + 1] = __float2bfloat16(xv.y - __bfloat162float(xh1));
  }
  // initial weight-ring prefetch; LDS-only barrier keeps it in flight
#pragma unroll
  for (int j = 0; j < PD_; ++j) load_enc(j);
  barrier_lds();

  // ================= ENCODER: 128 GRU steps, ONE LDS barrier per step =============
  // Invariant at step t entry: [cur] holds state S_{t-1} (S_{-1}=h0), sh_x[cur]=x_t,
  // weight-ring triples 0..PD-1 already in flight.
  int cur = 0;
  for (int t = 0; t < T_; ++t) {
    const int nxt = cur ^ 1;

    // early global issues: hs store of S_{t-1}; x_{t+1} load
    float2 xv;
    if (t + 1 < T_)
      xv = *(const float2*)(x + ((size_t)(b0 + mg) * T_ + (t + 1)) * F_ + cg * 2);
    if (t > 0) {
      uint4 hv = *(const uint4*)&sh_h[cur][mg * HSTR_ + cg * 8];
      *(uint4*)&hs[((size_t)(b0 + mg) * T_ + (t - 1)) * H_ + cg * 8] = hv;
    }

    // A-fragments from [cur]
#pragma unroll
    for (int kk = 0; kk < 8; ++kk) {
      ah[kk] = *(const bf16x8*)&sh_h[cur][l16 * HSTR_ + kk * 32 + quad * 8];
      al[kk] = *(const bf16x8*)&sh_l[cur][l16 * HSTR_ + kk * 32 + quad * 8];
    }
#pragma unroll
    for (int kk = 0; kk < 2; ++kk) {
      ax[kk]  = *(const bf16x8*)&sh_x[cur][l16 * XSTR_ + kk * 32 + quad * 8];
      axl[kk] = *(const bf16x8*)&sh_xl[cur][l16 * XSTR_ + kk * 32 + quad * 8];
    }

    f32x4 z4 = {0.f, 0.f, 0.f, 0.f};
    f32x4 ar0 = z4, az0 = z4, ani0 = z4, anh0 = z4;
    f32x4 ar1 = z4, az1 = z4, ani1 = z4, anh1 = z4;

#pragma unroll
    for (int j = 0; j < 20; ++j) {
      if (j < 8)       use_whh(j,      j & 7, ar0, az0, anh0);
      else if (j < 10) use_wih(j - 8,  j & 7, ar0, az0, ani0);
      else if (j < 18) use_whh(j - 10, j & 7, ar1, az1, anh1);
      else             use_wih(j - 18, j & 7, ar1, az1, ani1);
      if (j + PD_ < 20) load_enc(j + PD_);

      if (j == 9 || j == 19) {
        const int s2 = (j == 9) ? 0 : 1;
        const f32x4& ar = (j == 9) ? ar0 : ar1;
        const f32x4& az = (j == 9) ? az0 : az1;
        const f32x4& ani = (j == 9) ? ani0 : ani1;
        const f32x4& anh = (j == 9) ? anh0 : anh1;
        const int g = 16 * (2 * wid + s2) + l16;
        const float br_ = s_ebr[g], bz_ = s_ebz[g], bin_ = s_ebin[g], bhn_ = s_ebhn[g];
#pragma unroll
        for (int i = 0; i < 4; ++i) {
          const int m = quad * 4 + i;     // D row = batch
          float r = sigm_(ar[i] + br_);
          float z = sigm_(az[i] + bz_);
          float n = tanh_(ani[i] + bin_ + r * (anh[i] + bhn_));
          float hold = s_hf[cur][m * FSTR_ + g];
          float hn = (1.0f - z) * n + z * hold;
          s_hf[nxt][m * FSTR_ + g] = hn;
          __hip_bfloat16 hi = __float2bfloat16(hn);
          sh_h[nxt][m * HSTR_ + g] = hi;
          sh_l[nxt][m * HSTR_ + g] = __float2bfloat16(hn - __bfloat162float(hi));
        }
      }
      __builtin_amdgcn_sched_barrier(0);   // pin ring cadence (no load sinking)
    }

    // A/C dots for index t-1 (from s_hf[cur]); x_{t+1} -> sh_x[nxt]
    if (t > 0) {
      const float* hp = &s_hf[cur][mg * FSTR_ + cg * 8];
      float pa = 0.f, pc = 0.f;
#pragma unroll
      for (int j = 0; j < 8; ++j) {
        float hvf = hp[j];
        pa += hvf * s_wq[cg * 8 + j];
        pc += hvf * s_bq[cg * 8 + j];
      }
#pragma unroll
      for (int off = 16; off >= 1; off >>= 1) {
        pa += __shfl_xor(pa, off, 64);
        pc += __shfl_xor(pc, off, 64);
      }
      if (cg == 0) {
        s_A[mg * T_ + (t - 1)] = pa;
        s_C[mg * T_ + (t - 1)] = pc;
      }
    }
    if (t + 1 < T_) {
      __hip_bfloat16 xh0 = __float2bfloat16(xv.x);
      __hip_bfloat16 xh1 = __float2bfloat16(xv.y);
      sh_x[nxt][mg * XSTR_ + cg * 2]      = xh0;
      sh_x[nxt][mg * XSTR_ + cg * 2 + 1]  = xh1;
      sh_xl[nxt][mg * XSTR_ + cg * 2]     = __float2bfloat16(xv.x - __bfloat162float(xh0));
      sh_xl[nxt][mg * XSTR_ + cg * 2 + 1] = __float2bfloat16(xv.y - __bfloat162float(xh1));
      // cross-barrier ring refill for next step (stays in flight: no vmcnt drain)
#pragma unroll
      for (int j = 0; j < PD_; ++j) load_enc(j);
    }
    barrier_lds();
    cur = nxt;
  }

  // encoder epilogue: store hs[127] + A/C dots for idx 127 from [cur]
  {
    uint4 hv = *(const uint4*)&sh_h[cur][mg * HSTR_ + cg * 8];
    *(uint4*)&hs[((size_t)(b0 + mg) * T_ + (T_ - 1)) * H_ + cg * 8] = hv;
    const float* hp = &s_hf[cur][mg * FSTR_ + cg * 8];
    float pa = 0.f, pc = 0.f;
#pragma unroll
    for (int j = 0; j < 8; ++j) {
      float hvf = hp[j];
      pa += hvf * s_wq[cg * 8 + j];
      pc += hvf * s_bq[cg * 8 + j];
    }
#pragma unroll
    for (int off = 16; off >= 1; off >>= 1) {
      pa += __shfl_xor(pa, off, 64);
      pc += __shfl_xor(pc, off, 64);
    }
    if (cg == 0) {
      s_A[mg * T_ + (T_ - 1)] = pa;
      s_C[mg * T_ + (T_ - 1)] = pc;
    }
  }

  // ============================ DECODER: 32 steps ============================
  float prevr = x[((size_t)(b0 + mg) * T_ + (T_ - 1)) * F_];  // per-group prev
  if (tid < BT_)
    s_prev[tid] = x[((size_t)(b0 + tid) * T_ + (T_ - 1)) * F_];
  __syncthreads();   // FULL drain: hs stores must retire before P2 re-reads

  for (int s = 0; s < OUT_; ++s) {
    // P1: scores = (prev*A + C)*scale, softmax over T per batch row -> s_scr
    // (prev from register; same-32-lane-group LDS dataflow -> no barrier)
    {
      float4 a4 = *(const float4*)(s_A + mg * T_ + cg * 4);
      float4 c4 = *(const float4*)(s_C + mg * T_ + cg * 4);
      const float pv = prevr;
      float sc0 = (pv * a4.x + c4.x) * 0.0625f;
      float sc1 = (pv * a4.y + c4.y) * 0.0625f;
      float sc2 = (pv * a4.z + c4.z) * 0.0625f;
      float sc3 = (pv * a4.w + c4.w) * 0.0625f;
      float mx = fmaxf(fmaxf(sc0, sc1), fmaxf(sc2, sc3));
#pragma unroll
      for (int off = 16; off >= 1; off >>= 1) mx = fmaxf(mx, __shfl_xor(mx, off, 64));
      float e0 = __expf(sc0 - mx), e1 = __expf(sc1 - mx);
      float e2 = __expf(sc2 - mx), e3 = __expf(sc3 - mx);
      float ss = e0 + e1 + e2 + e3;
#pragma unroll
      for (int off = 16; off >= 1; off >>= 1) ss += __shfl_xor(ss, off, 64);
      const float inv = 1.0f / ss;
      float4 wv = make_float4(e0 * inv, e1 * inv, e2 * inv, e3 * inv);
      *(float4*)&s_scr[mg * SSTR_ + cg * 4] = wv;
    }

    // P2: ctx[m,h] = sum_t w[m,t] * hs[m,t,h]  (fp32 VALU, 8+8 uint4 in
    //     flight). hs stream first (critical path), then P3 ring prefetch.
    {
      float acc[8] = {0.f, 0.f, 0.f, 0.f, 0.f, 0.f, 0.f, 0.f};
      const __hip_bfloat16* hp = hs + (size_t)(b0 + mg) * T_ * H_ + cg * 8;
      const float* wp = &s_scr[mg * SSTR_];
      uint4 bA[8], bB[8];
#pragma unroll
      for (int u = 0; u < 8; ++u) bA[u] = *(const uint4*)(hp + (size_t)u * H_);
#pragma unroll
      for (int j = 0; j < PD_; ++j) load_dec(j);
      __builtin_amdgcn_sched_barrier(0);
      auto p2fma = [&](const uint4& hv, float wt) {
        acc[0] = fmaf(wt, __uint_as_float(hv.x << 16),         acc[0]);
        acc[1] = fmaf(wt, __uint_as_float(hv.x & 0xFFFF0000u), acc[1]);
        acc[2] = fmaf(wt, __uint_as_float(hv.y << 16),         acc[2]);
        acc[3] = fmaf(wt, __uint_as_float(hv.y & 0xFFFF0000u), acc[3]);
        acc[4] = fmaf(wt, __uint_as_float(hv.z << 16),         acc[4]);
        acc[5] = fmaf(wt, __uint_as_float(hv.z & 0xFFFF0000u), acc[5]);
        acc[6] = fmaf(wt, __uint_as_float(hv.w << 16),         acc[6]);
        acc[7] = fmaf(wt, __uint_as_float(hv.w & 0xFFFF0000u), acc[7]);
      };
      for (int tb = 0; tb < T_; tb += 16) {
#pragma unroll
        for (int u = 0; u < 8; ++u) bB[u] = *(const uint4*)(hp + (size_t)(tb + 8 + u) * H_);
#pragma unroll
        for (int u = 0; u < 8; ++u) p2fma(bA[u], wp[tb + u]);
        if (tb + 16 < T_) {
#pragma unroll
          for (int u = 0; u < 8; ++u) bA[u] = *(const uint4*)(hp + (size_t)(tb + 16 + u) * H_);
        }
#pragma unroll
        for (int u = 0; u < 8; ++u) p2fma(bB[u], wp[tb + 8 + u]);
      }
#pragma unroll
      for (int j = 0; j < 8; ++j) {
        float v = acc[j];
        s_hf[0][mg * FSTR_ + cg * 8 + j] = v;
        __hip_bfloat16 hi = __float2bfloat16(v);
        sh_h[0][mg * HSTR_ + cg * 8 + j] = hi;
        sh_l[0][mg * HSTR_ + cg * 8 + j] = __float2bfloat16(v - __bfloat162float(hi));
      }
    }
    barrier_lds();

    // P3: decoder GRU: gh = ctx @ dWhh^T (MFMA ring); gi = prev*dWih + b
    {
#pragma unroll
      for (int kk = 0; kk < 8; ++kk) {
        ah[kk] = *(const bf16x8*)&sh_h[0][l16 * HSTR_ + kk * 32 + quad * 8];
        al[kk] = *(const bf16x8*)&sh_l[0][l16 * HSTR_ + kk * 32 + quad * 8];
      }
      f32x4 z4 = {0.f, 0.f, 0.f, 0.f};
      f32x4 ar0 = z4, az0 = z4, anh0 = z4;
      f32x4 ar1 = z4, az1 = z4, anh1 = z4;
#pragma unroll
      for (int j = 0; j < 16; ++j) {
        if (j < 8) use_whh(j,     j & 7, ar0, az0, anh0);
        else       use_whh(j - 8, j & 7, ar1, az1, anh1);
        if (j + PD_ < 16) load_dec(j + PD_);

        if (j == 7 || j == 15) {
          const int s2 = (j == 7) ? 0 : 1;
          const f32x4& ar = (j == 7) ? ar0 : ar1;
          const f32x4& az = (j == 7) ? az0 : az1;
          const f32x4& anh = (j == 7) ? anh0 : anh1;
          const int g = 16 * (2 * wid + s2) + l16;
          const float dr = s_dbr[g], dz = s_dbz[g], din = s_dbin[g], dhn = s_dbhn[g];
          const float wir = s_dwih[g], wiz = s_dwih[H_ + g], win = s_dwih[2 * H_ + g];
#pragma unroll
          for (int i = 0; i < 4; ++i) {
            const int m = quad * 4 + i;
            const float pv = s_prev[m];
            float r = sigm_(ar[i] + pv * wir + dr);
            float z = sigm_(az[i] + pv * wiz + dz);
            float n = tanh_(pv * win + din + r * (anh[i] + dhn));
            float ctxv = s_hf[0][m * FSTR_ + g];
            float hd = (1.0f - z) * n + z * ctxv;
            __hip_bfloat16 hi = __float2bfloat16(hd);
            sh_h[1][m * HSTR_ + g] = hi;
            sh_l[1][m * HSTR_ + g] = __float2bfloat16(hd - __bfloat162float(hi));
          }
        }
        __builtin_amdgcn_sched_barrier(0);
      }
      // fc1 ring prefetch BEFORE the barrier: overlaps barrier + P4 frag reads
#pragma unroll
      for (int j = 0; j < PD_; ++j) load_fc(j);
    }
    barrier_lds();

    // P4: fc1 + relu (MFMA ring) -> fp32 in s_scr
    {
#pragma unroll
      for (int kk = 0; kk < 8; ++kk) {
        ah[kk] = *(const bf16x8*)&sh_h[1][l16 * HSTR_ + kk * 32 + quad * 8];  // ad
        al[kk] = *(const bf16x8*)&sh_l[1][l16 * HSTR_ + kk * 32 + quad * 8];  // adl
      }
      f32x4 z4 = {0.f, 0.f, 0.f, 0.f};
      f32x4 a10 = z4, a11 = z4;
#pragma unroll
      for (int j = 0; j < 16; ++j) {
        if (j < 8) use_fc(j,     j & 7, a10);
        else       use_fc(j - 8, j & 7, a11);
        if (j + PD_ < 16) load_fc(j + PD_);

        if (j == 7 || j == 15) {
          const int s2 = (j == 7) ? 0 : 1;
          const f32x4& a1 = (j == 7) ? a10 : a11;
          const int jcol = 16 * (2 * wid + s2) + l16;
          const float bj = s_f1b[jcol];
#pragma unroll
          for (int i = 0; i < 4; ++i) {
            const int m = quad * 4 + i;
            s_scr[m * SSTR_ + jcol] = fmaxf(a1[i] + bj, 0.0f);
          }
        }
        __builtin_amdgcn_sched_barrier(0);
      }
    }
    barrier_lds();

    // P5: fc2 (fp32 dot) -> out, update prev (register + LDS mirror)
    {
      const float* ap = &s_scr[mg * SSTR_ + cg * 8];
      float p = 0.f;
#pragma unroll
      for (int j = 0; j < 8; ++j)
        p += ap[j] * s_f2w[cg * 8 + j];
#pragma unroll
      for (int off = 16; off >= 1; off >>= 1) p += __shfl_xor(p, off, 64);
      float o = p + s_f2b;
      prevr = o;                        // all lanes of group hold the sum
      if (cg == 0) {
        s_prev[mg] = o;                 // for P3's cross-group read
        dout[(size_t)(b0 + mg) * OUT_ + s] = o;
      }
    }
    // no barrier: P1'/P2' touch only same-group rows; next cross-group
    // consumers (P3') are behind the P2'-end barrier.
  }
}

extern "C" void kernel_launch(void* const* d_in, const int* in_sizes, int n_in,
                              void* d_out, int out_size, void* d_ws, size_t ws_size,
                              hipStream_t stream) {
  (void)in_sizes; (void)n_in; (void)out_size; (void)ws_size;
  const float* x    = (const float*)d_in[0];
  const float* h0   = (const float*)d_in[1];
  const float* eWih = (const float*)d_in[2];
  const float* eWhh = (const float*)d_in[3];
  const float* ebih = (const float*)d_in[4];
  const float* ebhh = (const float*)d_in[5];
  const float* dWih = (const float*)d_in[6];
  const float* dWhh = (const float*)d_in[7];
  const float* dbih = (const float*)d_in[8];
  const float* dbhh = (const float*)d_in[9];
  const float* aWq  = (const float*)d_in[10];
  const float* abq  = (const float*)d_in[11];
  const float* f1W  = (const float*)d_in[12];
  const float* f1b  = (const float*)d_in[13];
  const float* f2W  = (const float*)d_in[14];
  const float* f2b  = (const float*)d_in[15];

  __hip_bfloat16* hs = (__hip_bfloat16*)d_ws;   // 134,217,728 B
  __hip_bfloat16* wb = (__hip_bfloat16*)((char*)d_ws + (size_t)B_ * T_ * H_ * 2);

  hipLaunchKernelGGL(af_convert_weights, dim3(256), dim3(256), 0, stream,
                     eWih, eWhh, dWhh, f1W, wb);
  hipLaunchKernelGGL(af_fused_kernel, dim3(NB_), dim3(NTH_), 0, stream,
                     x, h0, ebih, ebhh, dWih, dbih, dbhh, aWq, abq, f1b, f2W, f2b,
                     wb + PK_EIH_, wb + PK_EHH_, wb + PK_DHH_, wb + PK_F1_,
                     hs, (float*)d_out);
}

// Round 6
// 2386.511 us; speedup vs baseline: 1.2201x; 1.2201x over previous
//
#include <hip/hip_runtime.h>
#include <hip/hip_bf16.h>

// AttentiveFuturecaster: fused GRU-encoder + attentive GRU-decoder + FC head.
// Round 8 (base = R6's 1890us; R7's per-iteration sched_barrier pins REVERTED
// — they replicated m141's order-pinning failure, 2872us).
// Main change: LOOP-INVARIANT REGISTER-RESIDENT WEIGHTS. eWhh r/z gates
// (packed fragments, 128 VGPR) are loaded ONCE before the encoder loop and
// live across all 128 steps — the RA cannot sink/remat loop-invariant global
// loads, forcing the VGPR file to ~230 (budget 256 at LDS-capped 2 waves/
// SIMD). Streamed per step: only eWhh-n + eWih (28 loads/wave vs 60) via an
// 8-slot flat ring, one-ahead issue, refilled across the step barrier
// (barrier_lds: lgkmcnt-only, loads stay in flight). Decoder reloads the
// same arrays with dWhh r/z (once, amortized over 32 steps); streams dWhh-n
// (P3) and f1W (P4). Zero manual pins outside barrier_lds.
// Numerics bit-identical to R6 (same MFMA op order): absmax 0.0004882812.
// ws layout: [0, 128MB): hs bf16 [B,T,H]; then 1MB PACKED bf16 weight blob.

#define B_    2048
#define T_    128
#define F_    64
#define H_    256
#define OUT_  32
#define BT_   16
#define NTH_  512
#define NB_   (B_ / BT_)
#define HSTR_ 264   // bf16 h-tile LDS row stride
#define FSTR_ 260   // fp32 h-tile LDS row stride
#define XSTR_ 72    // bf16 x-tile LDS row stride
#define SSTR_ 260   // fp32 scratch row stride (softmax w / fc1 out)

// PACKED bf16 weight blob element offsets inside ws (after hs).
// Layout: chunks of 512 elements (1KB). eWhh/dWhh: chunk=((c*8+kk)*3+q),
// eWih: ((c*2+kk)*3+q), f1W: (c*8+kk). Within chunk: lane*8+e, where the
// fragment for lane (quad=lane>>4,l16=lane&15) is row q*H+16c+l16,
// cols kk*32+quad*8+e  — exactly the original per-lane load addresses.
#define PK_EHH_ 0
#define PK_EIH_ (PK_EHH_ + 3 * H_ * H_)    // 196608
#define PK_DHH_ (PK_EIH_ + 3 * H_ * F_)    // 245760
#define PK_F1_  (PK_DHH_ + 3 * H_ * H_)    // 442368
#define W_TOT_  (PK_F1_ + H_ * H_)         // 507904

typedef __attribute__((ext_vector_type(8))) short bf16x8;
typedef __attribute__((ext_vector_type(4))) float f32x4;

__device__ __forceinline__ f32x4 mfma16(bf16x8 a, bf16x8 b, f32x4 c) {
  return __builtin_amdgcn_mfma_f32_16x16x32_bf16(a, b, c, 0, 0, 0);
}
__device__ __forceinline__ float sigm_(float x) { return 1.0f / (1.0f + __expf(-x)); }
__device__ __forceinline__ float tanh_(float x) {
  x = fminf(15.0f, fmaxf(-15.0f, x));
  float e = __expf(2.0f * x);
  return (e - 1.0f) / (e + 1.0f);
}
// LDS-only barrier: does NOT drain vmcnt, so global (weight-ring) loads
// survive across it. sched_barrier fences code motion across the barrier
// (rule #18); these are the ONLY manual scheduling pins in the kernel.
__device__ __forceinline__ void barrier_lds() {
  __builtin_amdgcn_sched_barrier(0);
  asm volatile("s_waitcnt lgkmcnt(0)" ::: "memory");
  __builtin_amdgcn_s_barrier();
  __builtin_amdgcn_sched_barrier(0);
}

__global__ __launch_bounds__(256) void af_convert_weights(
    const float* __restrict__ eWih, const float* __restrict__ eWhh,
    const float* __restrict__ dWhh, const float* __restrict__ f1W,
    __hip_bfloat16* __restrict__ wb) {
  for (int i = blockIdx.x * blockDim.x + threadIdx.x; i < W_TOT_;
       i += gridDim.x * blockDim.x) {
    float v;
    int o, chunk, r, ln, e, q, ck, c, kk, row, col;
    if (i < PK_EIH_) {            // packed eWhh
      o = i;
      chunk = o >> 9; r = o & 511; ln = r >> 3; e = r & 7;
      q = chunk % 3; ck = chunk / 3; c = ck >> 3; kk = ck & 7;
      row = q * H_ + c * 16 + (ln & 15);
      col = kk * 32 + (ln >> 4) * 8 + e;
      v = eWhh[row * H_ + col];
    } else if (i < PK_DHH_) {     // packed eWih
      o = i - PK_EIH_;
      chunk = o >> 9; r = o & 511; ln = r >> 3; e = r & 7;
      q = chunk % 3; ck = chunk / 3; c = ck >> 1; kk = ck & 1;
      row = q * H_ + c * 16 + (ln & 15);
      col = kk * 32 + (ln >> 4) * 8 + e;
      v = eWih[row * F_ + col];
    } else if (i < PK_F1_) {      // packed dWhh
      o = i - PK_DHH_;
      chunk = o >> 9; r = o & 511; ln = r >> 3; e = r & 7;
      q = chunk % 3; ck = chunk / 3; c = ck >> 3; kk = ck & 7;
      row = q * H_ + c * 16 + (ln & 15);
      col = kk * 32 + (ln >> 4) * 8 + e;
      v = dWhh[row * H_ + col];
    } else {                      // packed f1W
      o = i - PK_F1_;
      chunk = o >> 9; r = o & 511; ln = r >> 3; e = r & 7;
      c = chunk >> 3; kk = chunk & 7;
      row = c * 16 + (ln & 15);
      col = kk * 32 + (ln >> 4) * 8 + e;
      v = f1W[row * H_ + col];
    }
    wb[i] = __float2bfloat16(v);
  }
}

__global__ __launch_bounds__(NTH_, 2) void af_fused_kernel(
    const float* __restrict__ x,
    const float* __restrict__ h0,
    const float* __restrict__ ebih,
    const float* __restrict__ ebhh,
    const float* __restrict__ dWih,
    const float* __restrict__ dbih,
    const float* __restrict__ dbhh,
    const float* __restrict__ aWq,
    const float* __restrict__ abq,
    const float* __restrict__ f1b,
    const float* __restrict__ f2W,
    const float* __restrict__ f2b,
    const __hip_bfloat16* __restrict__ eWihB,   // packed
    const __hip_bfloat16* __restrict__ eWhhB,   // packed
    const __hip_bfloat16* __restrict__ dWhhB,   // packed
    const __hip_bfloat16* __restrict__ f1WB,    // packed
    __hip_bfloat16* __restrict__ hs,     // [B,T,H] bf16 (workspace)
    float* __restrict__ dout)            // [B,OUT] fp32
{
  __shared__ __hip_bfloat16 sh_h[2][BT_ * HSTR_];   // h hi (bf16)
  __shared__ __hip_bfloat16 sh_l[2][BT_ * HSTR_];   // h lo (bf16 residual)
  __shared__ float          s_hf[2][BT_ * FSTR_];   // h fp32 (carried state)
  __shared__ __hip_bfloat16 sh_x[2][BT_ * XSTR_];   // x hi
  __shared__ __hip_bfloat16 sh_xl[2][BT_ * XSTR_];  // x lo
  __shared__ float s_A[BT_ * T_], s_C[BT_ * T_];    // rank-1 attention tables
  __shared__ float s_ebr[H_], s_ebz[H_], s_ebin[H_], s_ebhn[H_];
  __shared__ float s_dbr[H_], s_dbz[H_], s_dbin[H_], s_dbhn[H_];
  __shared__ float s_dwih[3 * H_];
  __shared__ float s_wq[H_], s_bq[H_], s_f1b[H_], s_f2w[H_];
  __shared__ float s_f2b;
  __shared__ float s_prev[BT_];
  __shared__ float s_scr[BT_ * SSTR_];  // softmax w (cols 0..127) / fc1 out (cols 0..255)

  const int tid  = threadIdx.x;
  const int b0   = blockIdx.x * BT_;
  const int lane = tid & 63;
  const int wid  = tid >> 6;     // 0..7
  const int quad = lane >> 4;    // 0..3
  const int l16  = lane & 15;    // 0..15
  const int mg   = tid >> 5;     // 0..15: batch row for 32-thread-group phases
  const int cg   = tid & 31;     // 0..31: position within group
  const int lofs = lane * 8;     // element offset within a packed 512-elem chunk

  // A-operand fragments + LOOP-INVARIANT resident weights + stream ring
  bf16x8 ah[8], al[8], ax[2], axl[2];
  bf16x8 wr_[2][8], wz_[2][8];   // resident r/z gates (128 VGPR): eWhh, then dWhh
  bf16x8 rs[8];                  // 8-slot flat stream ring (32 VGPR)

  // ---- streamed-item loaders (packed chunks, 1KB contiguous per wave) ----
  // encoder stream item i in [0,28): per c-block (s2=i<14?0:1):
  //   lo 0..7  -> eWhh n-gate chunk kk=lo
  //   lo 8..13 -> eWih (k=(lo-8)/3, gate g=(lo-8)%3)
  auto enc_load = [&](int i) {
    const int s2 = i < 14 ? 0 : 1;
    const int lo = i - s2 * 14;
    const int c  = 2 * wid + s2;
    const __hip_bfloat16* p;
    if (lo < 8) p = eWhhB + (size_t)((c * 8 + lo) * 3 + 2) * 512 + lofs;
    else {
      const int k = (lo - 8) / 3, g = (lo - 8) % 3;
      p = eWihB + (size_t)((c * 2 + k) * 3 + g) * 512 + lofs;
    }
    rs[i & 7] = *(const bf16x8*)p;
  };
  // decoder P3 stream: dWhh n-gate, item i in [0,16)
  auto dec_load = [&](int i) {
    const int s2 = i >> 3, kk = i & 7;
    rs[i & 7] = *(const bf16x8*)(
        dWhhB + (size_t)(((2 * wid + s2) * 8 + kk) * 3 + 2) * 512 + lofs);
  };
  // decoder P4 stream: f1W, item j in [0,16)
  auto fc_load = [&](int j) {
    rs[j & 7] = *(const bf16x8*)(
        f1WB + (size_t)((2 * wid + (j >> 3)) * 8 + (j & 7)) * 512 + lofs);
  };

  // ---------------- prologue: constants + h0 + x(t=0) into LDS ----------------
  for (int g = tid; g < H_; g += NTH_) {
    s_ebr[g]  = ebih[g]          + ebhh[g];
    s_ebz[g]  = ebih[H_ + g]     + ebhh[H_ + g];
    s_ebin[g] = ebih[2 * H_ + g];
    s_ebhn[g] = ebhh[2 * H_ + g];
    s_dbr[g]  = dbih[g]          + dbhh[g];
    s_dbz[g]  = dbih[H_ + g]     + dbhh[H_ + g];
    s_dbin[g] = dbih[2 * H_ + g];
    s_dbhn[g] = dbhh[2 * H_ + g];
    s_wq[g]   = aWq[g];
    s_bq[g]   = abq[g];
    s_f1b[g]  = f1b[g];
    s_f2w[g]  = f2W[g];
  }
  for (int g = tid; g < 3 * H_; g += NTH_) s_dwih[g] = dWih[g];
  if (tid == 0) s_f2b = f2b[0];

  {
    const float* hp = h0 + (size_t)(b0 + mg) * H_ + cg * 8;
    float4 v0 = *(const float4*)(hp);
    float4 v1 = *(const float4*)(hp + 4);
    float vv[8] = {v0.x, v0.y, v0.z, v0.w, v1.x, v1.y, v1.z, v1.w};
#pragma unroll
    for (int j = 0; j < 8; ++j) {
      float v = vv[j];
      s_hf[0][mg * FSTR_ + cg * 8 + j] = v;
      __hip_bfloat16 hi = __float2bfloat16(v);
      sh_h[0][mg * HSTR_ + cg * 8 + j] = hi;
      sh_l[0][mg * HSTR_ + cg * 8 + j] = __float2bfloat16(v - __bfloat162float(hi));
    }
    float2 xv = *(const float2*)(x + ((size_t)(b0 + mg) * T_) * F_ + cg * 2);
    __hip_bfloat16 xh0 = __float2bfloat16(xv.x);
    __hip_bfloat16 xh1 = __float2bfloat16(xv.y);
    sh_x[0][mg * XSTR_ + cg * 2]      = xh0;
    sh_x[0][mg * XSTR_ + cg * 2 + 1]  = xh1;
    sh_xl[0][mg * XSTR_ + cg * 2]     = __float2bfloat16(xv.x - __bfloat162float(xh0));
    sh_xl[0][mg * XSTR_ + cg * 2 + 1] = __float2bfloat16(xv.y - __bfloat162float(xh1));
  }

  // resident eWhh r/z gates (loop-invariant across all 128 steps)
#pragma unroll
  for (int s2 = 0; s2 < 2; ++s2)
#pragma unroll
    for (int kk = 0; kk < 8; ++kk) {
      const __hip_bfloat16* p =
          eWhhB + (size_t)(((2 * wid + s2) * 8 + kk) * 3) * 512 + lofs;
      wr_[s2][kk] = *(const bf16x8*)p;
      wz_[s2][kk] = *(const bf16x8*)(p + 512);
    }
  // initial stream-ring prefetch (stays in flight across barrier_lds)
#pragma unroll
  for (int j = 0; j < 8; ++j) enc_load(j);
  barrier_lds();

  // ================= ENCODER: 128 GRU steps, ONE LDS barrier per step =============
  // Invariant at step t entry: [cur] holds state S_{t-1} (S_{-1}=h0), sh_x[cur]=x_t,
  // stream items 0..7 in flight, wr_/wz_ resident.
  int cur = 0;
  for (int t = 0; t < T_; ++t) {
    const int nxt = cur ^ 1;

    // early global issues: hs store of S_{t-1}; x_{t+1} load
    float2 xv;
    if (t + 1 < T_)
      xv = *(const float2*)(x + ((size_t)(b0 + mg) * T_ + (t + 1)) * F_ + cg * 2);
    if (t > 0) {
      uint4 hv = *(const uint4*)&sh_h[cur][mg * HSTR_ + cg * 8];
      *(uint4*)&hs[((size_t)(b0 + mg) * T_ + (t - 1)) * H_ + cg * 8] = hv;
    }

    // A-fragments from [cur]
#pragma unroll
    for (int kk = 0; kk < 8; ++kk) {
      ah[kk] = *(const bf16x8*)&sh_h[cur][l16 * HSTR_ + kk * 32 + quad * 8];
      al[kk] = *(const bf16x8*)&sh_l[cur][l16 * HSTR_ + kk * 32 + quad * 8];
    }
#pragma unroll
    for (int kk = 0; kk < 2; ++kk) {
      ax[kk]  = *(const bf16x8*)&sh_x[cur][l16 * XSTR_ + kk * 32 + quad * 8];
      axl[kk] = *(const bf16x8*)&sh_xl[cur][l16 * XSTR_ + kk * 32 + quad * 8];
    }

    const f32x4 z4 = {0.f, 0.f, 0.f, 0.f};
#pragma unroll
    for (int s2 = 0; s2 < 2; ++s2) {
      f32x4 ar = z4, az = z4, ani = z4, anh = z4;
#pragma unroll
      for (int kk = 0; kk < 8; ++kk) {          // h-part: resident r/z, streamed n
        const int it = s2 * 14 + kk;
        bf16x8 bn = rs[it & 7];
        ar  = mfma16(al[kk], wr_[s2][kk], ar);  ar  = mfma16(ah[kk], wr_[s2][kk], ar);
        az  = mfma16(al[kk], wz_[s2][kk], az);  az  = mfma16(ah[kk], wz_[s2][kk], az);
        anh = mfma16(al[kk], bn, anh);          anh = mfma16(ah[kk], bn, anh);
        if (it + 8 < 28) enc_load(it + 8);
      }
#pragma unroll
      for (int k = 0; k < 2; ++k) {             // x-part: streamed r,z,n
        const int itb = s2 * 14 + 8 + 3 * k;
        bf16x8 qr = rs[itb & 7], qz = rs[(itb + 1) & 7], qn = rs[(itb + 2) & 7];
        ar  = mfma16(axl[k], qr, ar);  ar  = mfma16(ax[k], qr, ar);
        az  = mfma16(axl[k], qz, az);  az  = mfma16(ax[k], qz, az);
        ani = mfma16(axl[k], qn, ani); ani = mfma16(ax[k], qn, ani);
#pragma unroll
        for (int u = 0; u < 3; ++u)
          if (itb + 8 + u < 28) enc_load(itb + 8 + u);
      }
      // elementwise for this c-block
      {
        const int g = 16 * (2 * wid + s2) + l16;
        const float br_ = s_ebr[g], bz_ = s_ebz[g], bin_ = s_ebin[g], bhn_ = s_ebhn[g];
#pragma unroll
        for (int i = 0; i < 4; ++i) {
          const int m = quad * 4 + i;     // D row = batch
          float r = sigm_(ar[i] + br_);
          float z = sigm_(az[i] + bz_);
          float n = tanh_(ani[i] + bin_ + r * (anh[i] + bhn_));
          float hold = s_hf[cur][m * FSTR_ + g];
          float hn = (1.0f - z) * n + z * hold;
          s_hf[nxt][m * FSTR_ + g] = hn;
          __hip_bfloat16 hi = __float2bfloat16(hn);
          sh_h[nxt][m * HSTR_ + g] = hi;
          sh_l[nxt][m * HSTR_ + g] = __float2bfloat16(hn - __bfloat162float(hi));
        }
      }
    }

    // A/C dots for index t-1 (from s_hf[cur]); x_{t+1} -> sh_x[nxt]
    if (t > 0) {
      const float* hp = &s_hf[cur][mg * FSTR_ + cg * 8];
      float pa = 0.f, pc = 0.f;
#pragma unroll
      for (int j = 0; j < 8; ++j) {
        float hvf = hp[j];
        pa += hvf * s_wq[cg * 8 + j];
        pc += hvf * s_bq[cg * 8 + j];
      }
#pragma unroll
      for (int off = 16; off >= 1; off >>= 1) {
        pa += __shfl_xor(pa, off, 64);
        pc += __shfl_xor(pc, off, 64);
      }
      if (cg == 0) {
        s_A[mg * T_ + (t - 1)] = pa;
        s_C[mg * T_ + (t - 1)] = pc;
      }
    }
    if (t + 1 < T_) {
      __hip_bfloat16 xh0 = __float2bfloat16(xv.x);
      __hip_bfloat16 xh1 = __float2bfloat16(xv.y);
      sh_x[nxt][mg * XSTR_ + cg * 2]      = xh0;
      sh_x[nxt][mg * XSTR_ + cg * 2 + 1]  = xh1;
      sh_xl[nxt][mg * XSTR_ + cg * 2]     = __float2bfloat16(xv.x - __bfloat162float(xh0));
      sh_xl[nxt][mg * XSTR_ + cg * 2 + 1] = __float2bfloat16(xv.y - __bfloat162float(xh1));
      // cross-barrier stream refill for next step (no vmcnt drain at barrier)
#pragma unroll
      for (int j = 0; j < 8; ++j) enc_load(j);
    }
    barrier_lds();
    cur = nxt;
  }

  // encoder epilogue: store hs[127] + A/C dots for idx 127 from [cur]
  {
    uint4 hv = *(const uint4*)&sh_h[cur][mg * HSTR_ + cg * 8];
    *(uint4*)&hs[((size_t)(b0 + mg) * T_ + (T_ - 1)) * H_ + cg * 8] = hv;
    const float* hp = &s_hf[cur][mg * FSTR_ + cg * 8];
    float pa = 0.f, pc = 0.f;
#pragma unroll
    for (int j = 0; j < 8; ++j) {
      float hvf = hp[j];
      pa += hvf * s_wq[cg * 8 + j];
      pc += hvf * s_bq[cg * 8 + j];
    }
#pragma unroll
    for (int off = 16; off >= 1; off >>= 1) {
      pa += __shfl_xor(pa, off, 64);
      pc += __shfl_xor(pc, off, 64);
    }
    if (cg == 0) {
      s_A[mg * T_ + (T_ - 1)] = pa;
      s_C[mg * T_ + (T_ - 1)] = pc;
    }
  }

  // resident weights switch to decoder dWhh r/z (loop-invariant, 32 steps)
#pragma unroll
  for (int s2 = 0; s2 < 2; ++s2)
#pragma unroll
    for (int kk = 0; kk < 8; ++kk) {
      const __hip_bfloat16* p =
          dWhhB + (size_t)(((2 * wid + s2) * 8 + kk) * 3) * 512 + lofs;
      wr_[s2][kk] = *(const bf16x8*)p;
      wz_[s2][kk] = *(const bf16x8*)(p + 512);
    }

  // ============================ DECODER: 32 steps ============================
  float prevr = x[((size_t)(b0 + mg) * T_ + (T_ - 1)) * F_];  // per-group prev
  if (tid < BT_)
    s_prev[tid] = x[((size_t)(b0 + tid) * T_ + (T_ - 1)) * F_];
  __syncthreads();   // FULL drain: hs stores must retire before P2 re-reads

  for (int s = 0; s < OUT_; ++s) {
    // P1: scores = (prev*A + C)*scale, softmax over T per batch row -> s_scr
    // (prev from register; same-32-lane-group LDS dataflow -> no barrier)
    {
      float4 a4 = *(const float4*)(s_A + mg * T_ + cg * 4);
      float4 c4 = *(const float4*)(s_C + mg * T_ + cg * 4);
      const float pv = prevr;
      float sc0 = (pv * a4.x + c4.x) * 0.0625f;
      float sc1 = (pv * a4.y + c4.y) * 0.0625f;
      float sc2 = (pv * a4.z + c4.z) * 0.0625f;
      float sc3 = (pv * a4.w + c4.w) * 0.0625f;
      float mx = fmaxf(fmaxf(sc0, sc1), fmaxf(sc2, sc3));
#pragma unroll
      for (int off = 16; off >= 1; off >>= 1) mx = fmaxf(mx, __shfl_xor(mx, off, 64));
      float e0 = __expf(sc0 - mx), e1 = __expf(sc1 - mx);
      float e2 = __expf(sc2 - mx), e3 = __expf(sc3 - mx);
      float ss = e0 + e1 + e2 + e3;
#pragma unroll
      for (int off = 16; off >= 1; off >>= 1) ss += __shfl_xor(ss, off, 64);
      const float inv = 1.0f / ss;
      float4 wv = make_float4(e0 * inv, e1 * inv, e2 * inv, e3 * inv);
      *(float4*)&s_scr[mg * SSTR_ + cg * 4] = wv;
    }

    // P2: ctx[m,h] = sum_t w[m,t] * hs[m,t,h]  (fp32 VALU, 8+8 uint4 in
    //     flight). hs stream first (critical path), then P3 n-ring prefetch.
    {
      float acc[8] = {0.f, 0.f, 0.f, 0.f, 0.f, 0.f, 0.f, 0.f};
      const __hip_bfloat16* hp = hs + (size_t)(b0 + mg) * T_ * H_ + cg * 8;
      const float* wp = &s_scr[mg * SSTR_];
      uint4 bA[8], bB[8];
#pragma unroll
      for (int u = 0; u < 8; ++u) bA[u] = *(const uint4*)(hp + (size_t)u * H_);
#pragma unroll
      for (int j = 0; j < 8; ++j) dec_load(j);
      auto p2fma = [&](const uint4& hv, float wt) {
        acc[0] = fmaf(wt, __uint_as_float(hv.x << 16),         acc[0]);
        acc[1] = fmaf(wt, __uint_as_float(hv.x & 0xFFFF0000u), acc[1]);
        acc[2] = fmaf(wt, __uint_as_float(hv.y << 16),         acc[2]);
        acc[3] = fmaf(wt, __uint_as_float(hv.y & 0xFFFF0000u), acc[3]);
        acc[4] = fmaf(wt, __uint_as_float(hv.z << 16),         acc[4]);
        acc[5] = fmaf(wt, __uint_as_float(hv.z & 0xFFFF0000u), acc[5]);
        acc[6] = fmaf(wt, __uint_as_float(hv.w << 16),         acc[6]);
        acc[7] = fmaf(wt, __uint_as_float(hv.w & 0xFFFF0000u), acc[7]);
      };
      for (int tb = 0; tb < T_; tb += 16) {
#pragma unroll
        for (int u = 0; u < 8; ++u) bB[u] = *(const uint4*)(hp + (size_t)(tb + 8 + u) * H_);
#pragma unroll
        for (int u = 0; u < 8; ++u) p2fma(bA[u], wp[tb + u]);
        if (tb + 16 < T_) {
#pragma unroll
          for (int u = 0; u < 8; ++u) bA[u] = *(const uint4*)(hp + (size_t)(tb + 16 + u) * H_);
        }
#pragma unroll
        for (int u = 0; u < 8; ++u) p2fma(bB[u], wp[tb + 8 + u]);
      }
#pragma unroll
      for (int j = 0; j < 8; ++j) {
        float v = acc[j];
        s_hf[0][mg * FSTR_ + cg * 8 + j] = v;
        __hip_bfloat16 hi = __float2bfloat16(v);
        sh_h[0][mg * HSTR_ + cg * 8 + j] = hi;
        sh_l[0][mg * HSTR_ + cg * 8 + j] = __float2bfloat16(v - __bfloat162float(hi));
      }
    }
    barrier_lds();

    // P3: decoder GRU: gh = ctx @ dWhh^T (resident r/z + streamed n)
    {
#pragma unroll
      for (int kk = 0; kk < 8; ++kk) {
        ah[kk] = *(const bf16x8*)&sh_h[0][l16 * HSTR_ + kk * 32 + quad * 8];
        al[kk] = *(const bf16x8*)&sh_l[0][l16 * HSTR_ + kk * 32 + quad * 8];
      }
      const f32x4 z4 = {0.f, 0.f, 0.f, 0.f};
#pragma unroll
      for (int s2 = 0; s2 < 2; ++s2) {
        f32x4 ar = z4, az = z4, anh = z4;
#pragma unroll
        for (int kk = 0; kk < 8; ++kk) {
          const int it = s2 * 8 + kk;
          bf16x8 bn = rs[it & 7];
          ar  = mfma16(al[kk], wr_[s2][kk], ar);  ar  = mfma16(ah[kk], wr_[s2][kk], ar);
          az  = mfma16(al[kk], wz_[s2][kk], az);  az  = mfma16(ah[kk], wz_[s2][kk], az);
          anh = mfma16(al[kk], bn, anh);          anh = mfma16(ah[kk], bn, anh);
          if (it + 8 < 16) dec_load(it + 8);
        }
        const int g = 16 * (2 * wid + s2) + l16;
        const float dr = s_dbr[g], dz = s_dbz[g], din = s_dbin[g], dhn = s_dbhn[g];
        const float wir = s_dwih[g], wiz = s_dwih[H_ + g], win = s_dwih[2 * H_ + g];
#pragma unroll
        for (int i = 0; i < 4; ++i) {
          const int m = quad * 4 + i;
          const float pv = s_prev[m];
          float r = sigm_(ar[i] + pv * wir + dr);
          float z = sigm_(az[i] + pv * wiz + dz);
          float n = tanh_(pv * win + din + r * (anh[i] + dhn));
          float ctxv = s_hf[0][m * FSTR_ + g];
          float hd = (1.0f - z) * n + z * ctxv;
          __hip_bfloat16 hi = __float2bfloat16(hd);
          sh_h[1][m * HSTR_ + g] = hi;
          sh_l[1][m * HSTR_ + g] = __float2bfloat16(hd - __bfloat162float(hi));
        }
      }
      // fc1 ring prefetch BEFORE the barrier: overlaps barrier + P4 frag reads
#pragma unroll
      for (int j = 0; j < 8; ++j) fc_load(j);
    }
    barrier_lds();

    // P4: fc1 + relu (streamed f1W) -> fp32 in s_scr
    {
#pragma unroll
      for (int kk = 0; kk < 8; ++kk) {
        ah[kk] = *(const bf16x8*)&sh_h[1][l16 * HSTR_ + kk * 32 + quad * 8];  // ad
        al[kk] = *(const bf16x8*)&sh_l[1][l16 * HSTR_ + kk * 32 + quad * 8];  // adl
      }
      const f32x4 z4 = {0.f, 0.f, 0.f, 0.f};
#pragma unroll
      for (int s2 = 0; s2 < 2; ++s2) {
        f32x4 a1 = z4;
#pragma unroll
        for (int kk = 0; kk < 8; ++kk) {
          const int j = s2 * 8 + kk;
          bf16x8 bw = rs[j & 7];
          a1 = mfma16(al[kk], bw, a1);
          a1 = mfma16(ah[kk], bw, a1);
          if (j + 8 < 16) fc_load(j + 8);
        }
        const int jcol = 16 * (2 * wid + s2) + l16;
        const float bj = s_f1b[jcol];
#pragma unroll
        for (int i = 0; i < 4; ++i) {
          const int m = quad * 4 + i;
          s_scr[m * SSTR_ + jcol] = fmaxf(a1[i] + bj, 0.0f);
        }
      }
    }
    barrier_lds();

    // P5: fc2 (fp32 dot) -> out, update prev (register + LDS mirror)
    {
      const float* ap = &s_scr[mg * SSTR_ + cg * 8];
      float p = 0.f;
#pragma unroll
      for (int j = 0; j < 8; ++j)
        p += ap[j] * s_f2w[cg * 8 + j];
#pragma unroll
      for (int off = 16; off >= 1; off >>= 1) p += __shfl_xor(p, off, 64);
      float o = p + s_f2b;
      prevr = o;                        // all lanes of group hold the sum
      if (cg == 0) {
        s_prev[mg] = o;                 // for P3's cross-group read
        dout[(size_t)(b0 + mg) * OUT_ + s] = o;
      }
    }
    // no barrier: P1'/P2' touch only same-group rows; next cross-group
    // consumers (P3') are behind the P2'-end barrier.
  }
}

extern "C" void kernel_launch(void* const* d_in, const int* in_sizes, int n_in,
                              void* d_out, int out_size, void* d_ws, size_t ws_size,
                              hipStream_t stream) {
  (void)in_sizes; (void)n_in; (void)out_size; (void)ws_size;
  const float* x    = (const float*)d_in[0];
  const float* h0   = (const float*)d_in[1];
  const float* eWih = (const float*)d_in[2];
  const float* eWhh = (const float*)d_in[3];
  const float* ebih = (const float*)d_in[4];
  const float* ebhh = (const float*)d_in[5];
  const float* dWih = (const float*)d_in[6];
  const float* dWhh = (const float*)d_in[7];
  const float* dbih = (const float*)d_in[8];
  const float* dbhh = (const float*)d_in[9];
  const float* aWq  = (const float*)d_in[10];
  const float* abq  = (const float*)d_in[11];
  const float* f1W  = (const float*)d_in[12];
  const float* f1b  = (const float*)d_in[13];
  const float* f2W  = (const float*)d_in[14];
  const float* f2b  = (const float*)d_in[15];

  __hip_bfloat16* hs = (__hip_bfloat16*)d_ws;   // 134,217,728 B
  __hip_bfloat16* wb = (__hip_bfloat16*)((char*)d_ws + (size_t)B_ * T_ * H_ * 2);

  hipLaunchKernelGGL(af_convert_weights, dim3(256), dim3(256), 0, stream,
                     eWih, eWhh, dWhh, f1W, wb);
  hipLaunchKernelGGL(af_fused_kernel, dim3(NB_), dim3(NTH_), 0, stream,
                     x, h0, ebih, ebhh, dWih, dbih, dbhh, aWq, abq, f1b, f2W, f2b,
                     wb + PK_EIH_, wb + PK_EHH_, wb + PK_DHH_, wb + PK_F1_,
                     hs, (float*)d_out);
}

// Round 7
// 1956.752 us; speedup vs baseline: 1.4881x; 1.2196x over previous
//
#include <hip/hip_runtime.h>
#include <hip/hip_bf16.h>

// AttentiveFuturecaster: fused GRU-encoder + attentive GRU-decoder + FC head.
// Round 9 (base = R6, 1890us — best verified; R7 pins and R8 resident-weights
// both regressed and are reverted). Single change vs R6: A-FRAGMENT REGISTER
// DIET. R6 preloads 20 A-fragment pairs (~80 VGPR live all step), which at
// the compiler's hard 128-VGPR ceiling crowds out the PD=6 weight ring and
// collapses loads-in-flight to ~1-2 (60 serialized ~400cy waits = the ~10us/
// step stall; R8 disproved raw load-count as the lever). Now A-operands use a
// 2-chunk cur/next rotation (16 VGPR) refilled from LDS on demand inside the
// MFMA loop; the s2=1 pass re-reads the same 8 chunks (cheap ds_read_b128).
// Decoder P3/P4 get the same rotation. Ring/loads/barriers/MFMA operand
// values and order are byte-identical to R6 -> bit-identical numerics.
// ws layout: [0, 128MB): hs bf16 [B,T,H]; then 1MB PACKED bf16 weight blob.

#define B_    2048
#define T_    128
#define F_    64
#define H_    256
#define OUT_  32
#define BT_   16
#define NTH_  512
#define NB_   (B_ / BT_)
#define PD_   6     // weight-ring pipeline depth (gate-triples)
#define HSTR_ 264   // bf16 h-tile LDS row stride
#define FSTR_ 260   // fp32 h-tile LDS row stride
#define XSTR_ 72    // bf16 x-tile LDS row stride
#define SSTR_ 260   // fp32 scratch row stride (softmax w / fc1 out)

// PACKED bf16 weight blob element offsets inside ws (after hs).
// Layout: chunks of 512 elements (1KB). eWhh/dWhh: chunk=((c*8+kk)*3+q),
// eWih: ((c*2+kk)*3+q), f1W: (c*8+kk). Within chunk: lane*8+e, where the
// fragment for lane (quad=lane>>4,l16=lane&15) is row q*H+16c+l16,
// cols kk*32+quad*8+e  — exactly the original per-lane load addresses.
#define PK_EHH_ 0
#define PK_EIH_ (PK_EHH_ + 3 * H_ * H_)    // 196608
#define PK_DHH_ (PK_EIH_ + 3 * H_ * F_)    // 245760
#define PK_F1_  (PK_DHH_ + 3 * H_ * H_)    // 442368
#define W_TOT_  (PK_F1_ + H_ * H_)         // 507904

typedef __attribute__((ext_vector_type(8))) short bf16x8;
typedef __attribute__((ext_vector_type(4))) float f32x4;

__device__ __forceinline__ f32x4 mfma16(bf16x8 a, bf16x8 b, f32x4 c) {
  return __builtin_amdgcn_mfma_f32_16x16x32_bf16(a, b, c, 0, 0, 0);
}
__device__ __forceinline__ float sigm_(float x) { return 1.0f / (1.0f + __expf(-x)); }
__device__ __forceinline__ float tanh_(float x) {
  x = fminf(15.0f, fmaxf(-15.0f, x));
  float e = __expf(2.0f * x);
  return (e - 1.0f) / (e + 1.0f);
}

__global__ __launch_bounds__(256) void af_convert_weights(
    const float* __restrict__ eWih, const float* __restrict__ eWhh,
    const float* __restrict__ dWhh, const float* __restrict__ f1W,
    __hip_bfloat16* __restrict__ wb) {
  for (int i = blockIdx.x * blockDim.x + threadIdx.x; i < W_TOT_;
       i += gridDim.x * blockDim.x) {
    float v;
    int o, chunk, r, ln, e, q, ck, c, kk, row, col;
    if (i < PK_EIH_) {            // packed eWhh
      o = i;
      chunk = o >> 9; r = o & 511; ln = r >> 3; e = r & 7;
      q = chunk % 3; ck = chunk / 3; c = ck >> 3; kk = ck & 7;
      row = q * H_ + c * 16 + (ln & 15);
      col = kk * 32 + (ln >> 4) * 8 + e;
      v = eWhh[row * H_ + col];
    } else if (i < PK_DHH_) {     // packed eWih
      o = i - PK_EIH_;
      chunk = o >> 9; r = o & 511; ln = r >> 3; e = r & 7;
      q = chunk % 3; ck = chunk / 3; c = ck >> 1; kk = ck & 1;
      row = q * H_ + c * 16 + (ln & 15);
      col = kk * 32 + (ln >> 4) * 8 + e;
      v = eWih[row * F_ + col];
    } else if (i < PK_F1_) {      // packed dWhh
      o = i - PK_DHH_;
      chunk = o >> 9; r = o & 511; ln = r >> 3; e = r & 7;
      q = chunk % 3; ck = chunk / 3; c = ck >> 3; kk = ck & 7;
      row = q * H_ + c * 16 + (ln & 15);
      col = kk * 32 + (ln >> 4) * 8 + e;
      v = dWhh[row * H_ + col];
    } else {                      // packed f1W
      o = i - PK_F1_;
      chunk = o >> 9; r = o & 511; ln = r >> 3; e = r & 7;
      c = chunk >> 3; kk = chunk & 7;
      row = c * 16 + (ln & 15);
      col = kk * 32 + (ln >> 4) * 8 + e;
      v = f1W[row * H_ + col];
    }
    wb[i] = __float2bfloat16(v);
  }
}

__global__ __launch_bounds__(NTH_, 2) void af_fused_kernel(
    const float* __restrict__ x,
    const float* __restrict__ h0,
    const float* __restrict__ ebih,
    const float* __restrict__ ebhh,
    const float* __restrict__ dWih,
    const float* __restrict__ dbih,
    const float* __restrict__ dbhh,
    const float* __restrict__ aWq,
    const float* __restrict__ abq,
    const float* __restrict__ f1b,
    const float* __restrict__ f2W,
    const float* __restrict__ f2b,
    const __hip_bfloat16* __restrict__ eWihB,   // packed
    const __hip_bfloat16* __restrict__ eWhhB,   // packed
    const __hip_bfloat16* __restrict__ dWhhB,   // packed
    const __hip_bfloat16* __restrict__ f1WB,    // packed
    __hip_bfloat16* __restrict__ hs,     // [B,T,H] bf16 (workspace)
    float* __restrict__ dout)            // [B,OUT] fp32
{
  __shared__ __hip_bfloat16 sh_h[2][BT_ * HSTR_];   // h hi (bf16)
  __shared__ __hip_bfloat16 sh_l[2][BT_ * HSTR_];   // h lo (bf16 residual)
  __shared__ float          s_hf[2][BT_ * FSTR_];   // h fp32 (carried state)
  __shared__ __hip_bfloat16 sh_x[2][BT_ * XSTR_];   // x hi
  __shared__ __hip_bfloat16 sh_xl[2][BT_ * XSTR_];  // x lo
  __shared__ float s_A[BT_ * T_], s_C[BT_ * T_];    // rank-1 attention tables
  __shared__ float s_ebr[H_], s_ebz[H_], s_ebin[H_], s_ebhn[H_];
  __shared__ float s_dbr[H_], s_dbz[H_], s_dbin[H_], s_dbhn[H_];
  __shared__ float s_dwih[3 * H_];
  __shared__ float s_wq[H_], s_bq[H_], s_f1b[H_], s_f2w[H_];
  __shared__ float s_f2b;
  __shared__ float s_prev[BT_];
  __shared__ float s_scr[BT_ * SSTR_];  // softmax w (cols 0..127) / fc1 out (cols 0..255)

  const int tid  = threadIdx.x;
  const int b0   = blockIdx.x * BT_;
  const int lane = tid & 63;
  const int wid  = tid >> 6;     // 0..7
  const int quad = lane >> 4;    // 0..3
  const int l16  = lane & 15;    // 0..15
  const int mg   = tid >> 5;     // 0..15: batch row for 32-thread-group phases
  const int cg   = tid & 31;     // 0..31: position within group
  const int lofs = lane * 8;     // element offset within a packed 512-elem chunk
  const int aoff = l16 * HSTR_ + quad * 8;   // A-fragment base offset (bf16 els)

  // A-operand rotation (2 chunks live) + x-fragments + weight register ring
  bf16x8 ax[2], axl[2];
  bf16x8 rb[PD_], rz[PD_], rn[PD_];

  // ---- pipelined weight loaders: packed chunks, 1KB contiguous per wave ----
  auto load_enc = [&](int j) {            // j in [0,20)
    const int slot = j % PD_;
    const int s2 = j < 10 ? 0 : 1;
    const int lo = j - s2 * 10;
    const int c = 2 * wid + s2;
    const __hip_bfloat16* p;
    if (lo < 8) p = eWhhB + (size_t)((c * 8 + lo) * 3) * 512 + lofs;
    else        p = eWihB + (size_t)((c * 2 + (lo - 8)) * 3) * 512 + lofs;
    rb[slot] = *(const bf16x8*)p;
    rz[slot] = *(const bf16x8*)(p + 512);
    rn[slot] = *(const bf16x8*)(p + 1024);
  };
  auto load_dec = [&](int j) {            // j in [0,16)
    const int slot = j % PD_;
    const __hip_bfloat16* p =
        dWhhB + (size_t)(((2 * wid + (j >> 3)) * 8 + (j & 7)) * 3) * 512 + lofs;
    rb[slot] = *(const bf16x8*)p;
    rz[slot] = *(const bf16x8*)(p + 512);
    rn[slot] = *(const bf16x8*)(p + 1024);
  };
  auto load_fc = [&](int j) {             // j in [0,16)
    const int slot = j % PD_;
    rb[slot] = *(const bf16x8*)(
        f1WB + (size_t)((2 * wid + (j >> 3)) * 8 + (j & 7)) * 512 + lofs);
  };
  // ---- consumers (lo-split MFMA; operand values/order identical to R6) ----
  auto use_whh = [&](bf16x8 a_l, bf16x8 a_h, int slot,
                     f32x4& ar, f32x4& az, f32x4& anh) {
    ar  = mfma16(a_l, rb[slot], ar);  ar  = mfma16(a_h, rb[slot], ar);
    az  = mfma16(a_l, rz[slot], az);  az  = mfma16(a_h, rz[slot], az);
    anh = mfma16(a_l, rn[slot], anh); anh = mfma16(a_h, rn[slot], anh);
  };
  auto use_wih = [&](int kk, int slot, f32x4& ar, f32x4& az, f32x4& ani) {
    ar  = mfma16(axl[kk], rb[slot], ar);  ar  = mfma16(ax[kk], rb[slot], ar);
    az  = mfma16(axl[kk], rz[slot], az);  az  = mfma16(ax[kk], rz[slot], az);
    ani = mfma16(axl[kk], rn[slot], ani); ani = mfma16(ax[kk], rn[slot], ani);
  };
  auto use_fc = [&](bf16x8 a_l, bf16x8 a_h, int slot, f32x4& a1) {
    a1 = mfma16(a_l, rb[slot], a1);
    a1 = mfma16(a_h, rb[slot], a1);
  };

  // ---------------- prologue: constants + h0 + x(t=0) into LDS ----------------
  for (int g = tid; g < H_; g += NTH_) {
    s_ebr[g]  = ebih[g]          + ebhh[g];
    s_ebz[g]  = ebih[H_ + g]     + ebhh[H_ + g];
    s_ebin[g] = ebih[2 * H_ + g];
    s_ebhn[g] = ebhh[2 * H_ + g];
    s_dbr[g]  = dbih[g]          + dbhh[g];
    s_dbz[g]  = dbih[H_ + g]     + dbhh[H_ + g];
    s_dbin[g] = dbih[2 * H_ + g];
    s_dbhn[g] = dbhh[2 * H_ + g];
    s_wq[g]   = aWq[g];
    s_bq[g]   = abq[g];
    s_f1b[g]  = f1b[g];
    s_f2w[g]  = f2W[g];
  }
  for (int g = tid; g < 3 * H_; g += NTH_) s_dwih[g] = dWih[g];
  if (tid == 0) s_f2b = f2b[0];

  {
    const float* hp = h0 + (size_t)(b0 + mg) * H_ + cg * 8;
    float4 v0 = *(const float4*)(hp);
    float4 v1 = *(const float4*)(hp + 4);
    float vv[8] = {v0.x, v0.y, v0.z, v0.w, v1.x, v1.y, v1.z, v1.w};
#pragma unroll
    for (int j = 0; j < 8; ++j) {
      float v = vv[j];
      s_hf[0][mg * FSTR_ + cg * 8 + j] = v;
      __hip_bfloat16 hi = __float2bfloat16(v);
      sh_h[0][mg * HSTR_ + cg * 8 + j] = hi;
      sh_l[0][mg * HSTR_ + cg * 8 + j] = __float2bfloat16(v - __bfloat162float(hi));
    }
    float2 xv = *(const float2*)(x + ((size_t)(b0 + mg) * T_) * F_ + cg * 2);
    __hip_bfloat16 xh0 = __float2bfloat16(xv.x);
    __hip_bfloat16 xh1 = __float2bfloat16(xv.y);
    sh_x[0][mg * XSTR_ + cg * 2]      = xh0;
    sh_x[0][mg * XSTR_ + cg * 2 + 1]  = xh1;
    sh_xl[0][mg * XSTR_ + cg * 2]     = __float2bfloat16(xv.x - __bfloat162float(xh0));
    sh_xl[0][mg * XSTR_ + cg * 2 + 1] = __float2bfloat16(xv.y - __bfloat162float(xh1));
  }
  // initial weight-ring prefetch (overlaps the prologue barrier)
#pragma unroll
  for (int j = 0; j < PD_; ++j) load_enc(j);
  __syncthreads();

  // ================= ENCODER: 128 GRU steps, ONE barrier per step =================
  // Invariant at step t entry: [cur] holds state S_{t-1} (S_{-1}=h0), sh_x[cur]=x_t.
  int cur = 0;
  for (int t = 0; t < T_; ++t) {
    const int nxt = cur ^ 1;

    // early global issues: hs store of S_{t-1}; x_{t+1} load
    float2 xv;
    if (t + 1 < T_)
      xv = *(const float2*)(x + ((size_t)(b0 + mg) * T_ + (t + 1)) * F_ + cg * 2);
    if (t > 0) {
      uint4 hv = *(const uint4*)&sh_h[cur][mg * HSTR_ + cg * 8];
      *(uint4*)&hs[((size_t)(b0 + mg) * T_ + (t - 1)) * H_ + cg * 8] = hv;
    }

    // x-fragments from [cur]; A-rotation prologue (chunks 0,1)
#pragma unroll
    for (int kk = 0; kk < 2; ++kk) {
      ax[kk]  = *(const bf16x8*)&sh_x[cur][l16 * XSTR_ + kk * 32 + quad * 8];
      axl[kk] = *(const bf16x8*)&sh_xl[cur][l16 * XSTR_ + kk * 32 + quad * 8];
    }
    bf16x8 cah = *(const bf16x8*)&sh_h[cur][aoff];
    bf16x8 cal = *(const bf16x8*)&sh_l[cur][aoff];
    bf16x8 nah = *(const bf16x8*)&sh_h[cur][aoff + 32];
    bf16x8 nal = *(const bf16x8*)&sh_l[cur][aoff + 32];

    f32x4 z4 = {0.f, 0.f, 0.f, 0.f};
    f32x4 ar0 = z4, az0 = z4, ani0 = z4, anh0 = z4;
    f32x4 ar1 = z4, az1 = z4, ani1 = z4, anh1 = z4;

    // h-position hp for iteration j: j<8 -> hp=j; 10<=j<18 -> hp=j-2.
    // Invariant at each h-iteration: (cah,cal)=chunk(hp&7... chunk(hp mod 8)),
    // (nah,nal)=chunk(hp+1). After consume: rotate + load chunk(hp+2).
#pragma unroll
    for (int j = 0; j < 20; ++j) {
      if (j < 8 || (j >= 10 && j < 18)) {
        const int hp = (j < 8) ? j : (j - 2);
        if (j < 8) use_whh(cal, cah, j % PD_, ar0, az0, anh0);
        else       use_whh(cal, cah, j % PD_, ar1, az1, anh1);
        cah = nah; cal = nal;
        if (hp + 2 < 16) {
          const int nk = (hp + 2) & 7;
          nah = *(const bf16x8*)&sh_h[cur][aoff + nk * 32];
          nal = *(const bf16x8*)&sh_l[cur][aoff + nk * 32];
        }
      } else if (j < 10) {
        use_wih(j - 8, j % PD_, ar0, az0, ani0);
      } else {
        use_wih(j - 18, j % PD_, ar1, az1, ani1);
      }
      if (j + PD_ < 20) load_enc(j + PD_);

      if (j == 9 || j == 19) {
        const int s2 = (j == 9) ? 0 : 1;
        const f32x4& ar = (j == 9) ? ar0 : ar1;
        const f32x4& az = (j == 9) ? az0 : az1;
        const f32x4& ani = (j == 9) ? ani0 : ani1;
        const f32x4& anh = (j == 9) ? anh0 : anh1;
        const int g = 16 * (2 * wid + s2) + l16;
        const float br_ = s_ebr[g], bz_ = s_ebz[g], bin_ = s_ebin[g], bhn_ = s_ebhn[g];
#pragma unroll
        for (int i = 0; i < 4; ++i) {
          const int m = quad * 4 + i;     // D row = batch
          float r = sigm_(ar[i] + br_);
          float z = sigm_(az[i] + bz_);
          float n = tanh_(ani[i] + bin_ + r * (anh[i] + bhn_));
          float hold = s_hf[cur][m * FSTR_ + g];
          float hn = (1.0f - z) * n + z * hold;
          s_hf[nxt][m * FSTR_ + g] = hn;
          __hip_bfloat16 hi = __float2bfloat16(hn);
          sh_h[nxt][m * HSTR_ + g] = hi;
          sh_l[nxt][m * HSTR_ + g] = __float2bfloat16(hn - __bfloat162float(hi));
        }
      }
    }

    // A/C dots for index t-1 (from s_hf[cur]); x_{t+1} -> sh_x[nxt]
    if (t > 0) {
      const float* hp = &s_hf[cur][mg * FSTR_ + cg * 8];
      float pa = 0.f, pc = 0.f;
#pragma unroll
      for (int j = 0; j < 8; ++j) {
        float hvf = hp[j];
        pa += hvf * s_wq[cg * 8 + j];
        pc += hvf * s_bq[cg * 8 + j];
      }
#pragma unroll
      for (int off = 16; off >= 1; off >>= 1) {
        pa += __shfl_xor(pa, off, 64);
        pc += __shfl_xor(pc, off, 64);
      }
      if (cg == 0) {
        s_A[mg * T_ + (t - 1)] = pa;
        s_C[mg * T_ + (t - 1)] = pc;
      }
    }
    if (t + 1 < T_) {
      __hip_bfloat16 xh0 = __float2bfloat16(xv.x);
      __hip_bfloat16 xh1 = __float2bfloat16(xv.y);
      sh_x[nxt][mg * XSTR_ + cg * 2]      = xh0;
      sh_x[nxt][mg * XSTR_ + cg * 2 + 1]  = xh1;
      sh_xl[nxt][mg * XSTR_ + cg * 2]     = __float2bfloat16(xv.x - __bfloat162float(xh0));
      sh_xl[nxt][mg * XSTR_ + cg * 2 + 1] = __float2bfloat16(xv.y - __bfloat162float(xh1));
      // cross-barrier ring refill for next step
#pragma unroll
      for (int j = 0; j < PD_; ++j) load_enc(j);
    }
    __syncthreads();
    cur = nxt;
  }

  // encoder epilogue: store hs[127] + A/C dots for idx 127 from [cur]
  {
    uint4 hv = *(const uint4*)&sh_h[cur][mg * HSTR_ + cg * 8];
    *(uint4*)&hs[((size_t)(b0 + mg) * T_ + (T_ - 1)) * H_ + cg * 8] = hv;
    const float* hp = &s_hf[cur][mg * FSTR_ + cg * 8];
    float pa = 0.f, pc = 0.f;
#pragma unroll
    for (int j = 0; j < 8; ++j) {
      float hvf = hp[j];
      pa += hvf * s_wq[cg * 8 + j];
      pc += hvf * s_bq[cg * 8 + j];
    }
#pragma unroll
    for (int off = 16; off >= 1; off >>= 1) {
      pa += __shfl_xor(pa, off, 64);
      pc += __shfl_xor(pc, off, 64);
    }
    if (cg == 0) {
      s_A[mg * T_ + (T_ - 1)] = pa;
      s_C[mg * T_ + (T_ - 1)] = pc;
    }
  }

  // ============================ DECODER: 32 steps ============================
  float prevr = x[((size_t)(b0 + mg) * T_ + (T_ - 1)) * F_];  // per-group prev
  if (tid < BT_)
    s_prev[tid] = x[((size_t)(b0 + tid) * T_ + (T_ - 1)) * F_];
  __syncthreads();

  for (int s = 0; s < OUT_; ++s) {
    // P1: scores = (prev*A + C)*scale, softmax over T per batch row -> s_scr
    // (prev from register; same-32-lane-group LDS dataflow -> no barrier)
    {
      float4 a4 = *(const float4*)(s_A + mg * T_ + cg * 4);
      float4 c4 = *(const float4*)(s_C + mg * T_ + cg * 4);
      const float pv = prevr;
      float sc0 = (pv * a4.x + c4.x) * 0.0625f;
      float sc1 = (pv * a4.y + c4.y) * 0.0625f;
      float sc2 = (pv * a4.z + c4.z) * 0.0625f;
      float sc3 = (pv * a4.w + c4.w) * 0.0625f;
      float mx = fmaxf(fmaxf(sc0, sc1), fmaxf(sc2, sc3));
#pragma unroll
      for (int off = 16; off >= 1; off >>= 1) mx = fmaxf(mx, __shfl_xor(mx, off, 64));
      float e0 = __expf(sc0 - mx), e1 = __expf(sc1 - mx);
      float e2 = __expf(sc2 - mx), e3 = __expf(sc3 - mx);
      float ss = e0 + e1 + e2 + e3;
#pragma unroll
      for (int off = 16; off >= 1; off >>= 1) ss += __shfl_xor(ss, off, 64);
      const float inv = 1.0f / ss;
      float4 wv = make_float4(e0 * inv, e1 * inv, e2 * inv, e3 * inv);
      *(float4*)&s_scr[mg * SSTR_ + cg * 4] = wv;
    }

    // P2: ctx[m,h] = sum_t w[m,t] * hs[m,t,h]  (fp32 VALU, 8+8 uint4 in
    //     flight). hs stream first (critical path), then P3 ring prefetch.
    {
      float acc[8] = {0.f, 0.f, 0.f, 0.f, 0.f, 0.f, 0.f, 0.f};
      const __hip_bfloat16* hp = hs + (size_t)(b0 + mg) * T_ * H_ + cg * 8;
      const float* wp = &s_scr[mg * SSTR_];
      uint4 bA[8], bB[8];
#pragma unroll
      for (int u = 0; u < 8; ++u) bA[u] = *(const uint4*)(hp + (size_t)u * H_);
#pragma unroll
      for (int j = 0; j < PD_; ++j) load_dec(j);
      auto p2fma = [&](const uint4& hv, float wt) {
        acc[0] = fmaf(wt, __uint_as_float(hv.x << 16),         acc[0]);
        acc[1] = fmaf(wt, __uint_as_float(hv.x & 0xFFFF0000u), acc[1]);
        acc[2] = fmaf(wt, __uint_as_float(hv.y << 16),         acc[2]);
        acc[3] = fmaf(wt, __uint_as_float(hv.y & 0xFFFF0000u), acc[3]);
        acc[4] = fmaf(wt, __uint_as_float(hv.z << 16),         acc[4]);
        acc[5] = fmaf(wt, __uint_as_float(hv.z & 0xFFFF0000u), acc[5]);
        acc[6] = fmaf(wt, __uint_as_float(hv.w << 16),         acc[6]);
        acc[7] = fmaf(wt, __uint_as_float(hv.w & 0xFFFF0000u), acc[7]);
      };
      for (int tb = 0; tb < T_; tb += 16) {
#pragma unroll
        for (int u = 0; u < 8; ++u) bB[u] = *(const uint4*)(hp + (size_t)(tb + 8 + u) * H_);
#pragma unroll
        for (int u = 0; u < 8; ++u) p2fma(bA[u], wp[tb + u]);
        if (tb + 16 < T_) {
#pragma unroll
          for (int u = 0; u < 8; ++u) bA[u] = *(const uint4*)(hp + (size_t)(tb + 16 + u) * H_);
        }
#pragma unroll
        for (int u = 0; u < 8; ++u) p2fma(bB[u], wp[tb + 8 + u]);
      }
#pragma unroll
      for (int j = 0; j < 8; ++j) {
        float v = acc[j];
        s_hf[0][mg * FSTR_ + cg * 8 + j] = v;
        __hip_bfloat16 hi = __float2bfloat16(v);
        sh_h[0][mg * HSTR_ + cg * 8 + j] = hi;
        sh_l[0][mg * HSTR_ + cg * 8 + j] = __float2bfloat16(v - __bfloat162float(hi));
      }
    }
    __syncthreads();

    // P3: decoder GRU: gh = ctx @ dWhh^T (MFMA ring, A-rotation from sh_h[0])
    {
      bf16x8 cah = *(const bf16x8*)&sh_h[0][aoff];
      bf16x8 cal = *(const bf16x8*)&sh_l[0][aoff];
      bf16x8 nah = *(const bf16x8*)&sh_h[0][aoff + 32];
      bf16x8 nal = *(const bf16x8*)&sh_l[0][aoff + 32];
      f32x4 z4 = {0.f, 0.f, 0.f, 0.f};
      f32x4 ar0 = z4, az0 = z4, anh0 = z4;
      f32x4 ar1 = z4, az1 = z4, anh1 = z4;
#pragma unroll
      for (int j = 0; j < 16; ++j) {
        if (j < 8) use_whh(cal, cah, j % PD_, ar0, az0, anh0);
        else       use_whh(cal, cah, j % PD_, ar1, az1, anh1);
        cah = nah; cal = nal;
        if (j + 2 < 16) {
          const int nk = (j + 2) & 7;
          nah = *(const bf16x8*)&sh_h[0][aoff + nk * 32];
          nal = *(const bf16x8*)&sh_l[0][aoff + nk * 32];
        }
        if (j + PD_ < 16) load_dec(j + PD_);

        if (j == 7 || j == 15) {
          const int s2 = (j == 7) ? 0 : 1;
          const f32x4& ar = (j == 7) ? ar0 : ar1;
          const f32x4& az = (j == 7) ? az0 : az1;
          const f32x4& anh = (j == 7) ? anh0 : anh1;
          const int g = 16 * (2 * wid + s2) + l16;
          const float dr = s_dbr[g], dz = s_dbz[g], din = s_dbin[g], dhn = s_dbhn[g];
          const float wir = s_dwih[g], wiz = s_dwih[H_ + g], win = s_dwih[2 * H_ + g];
#pragma unroll
          for (int i = 0; i < 4; ++i) {
            const int m = quad * 4 + i;
            const float pv = s_prev[m];
            float r = sigm_(ar[i] + pv * wir + dr);
            float z = sigm_(az[i] + pv * wiz + dz);
            float n = tanh_(pv * win + din + r * (anh[i] + dhn));
            float ctxv = s_hf[0][m * FSTR_ + g];
            float hd = (1.0f - z) * n + z * ctxv;
            __hip_bfloat16 hi = __float2bfloat16(hd);
            sh_h[1][m * HSTR_ + g] = hi;
            sh_l[1][m * HSTR_ + g] = __float2bfloat16(hd - __bfloat162float(hi));
          }
        }
      }
    }
    __syncthreads();

    // P4: fc1 + relu (MFMA ring, A-rotation from sh_h[1]) -> fp32 in s_scr
    {
      bf16x8 cah = *(const bf16x8*)&sh_h[1][aoff];
      bf16x8 cal = *(const bf16x8*)&sh_l[1][aoff];
      bf16x8 nah = *(const bf16x8*)&sh_h[1][aoff + 32];
      bf16x8 nal = *(const bf16x8*)&sh_l[1][aoff + 32];
#pragma unroll
      for (int j = 0; j < PD_; ++j) load_fc(j);
      f32x4 z4 = {0.f, 0.f, 0.f, 0.f};
      f32x4 a10 = z4, a11 = z4;
#pragma unroll
      for (int j = 0; j < 16; ++j) {
        if (j < 8) use_fc(cal, cah, j % PD_, a10);
        else       use_fc(cal, cah, j % PD_, a11);
        cah = nah; cal = nal;
        if (j + 2 < 16) {
          const int nk = (j + 2) & 7;
          nah = *(const bf16x8*)&sh_h[1][aoff + nk * 32];
          nal = *(const bf16x8*)&sh_l[1][aoff + nk * 32];
        }
        if (j + PD_ < 16) load_fc(j + PD_);

        if (j == 7 || j == 15) {
          const int s2 = (j == 7) ? 0 : 1;
          const f32x4& a1 = (j == 7) ? a10 : a11;
          const int jcol = 16 * (2 * wid + s2) + l16;
          const float bj = s_f1b[jcol];
#pragma unroll
          for (int i = 0; i < 4; ++i) {
            const int m = quad * 4 + i;
            s_scr[m * SSTR_ + jcol] = fmaxf(a1[i] + bj, 0.0f);
          }
        }
      }
    }
    __syncthreads();

    // P5: fc2 (fp32 dot) -> out, update prev (register + LDS mirror)
    {
      const float* ap = &s_scr[mg * SSTR_ + cg * 8];
      float p = 0.f;
#pragma unroll
      for (int j = 0; j < 8; ++j)
        p += ap[j] * s_f2w[cg * 8 + j];
#pragma unroll
      for (int off = 16; off >= 1; off >>= 1) p += __shfl_xor(p, off, 64);
      float o = p + s_f2b;
      prevr = o;                        // all lanes of group hold the sum
      if (cg == 0) {
        s_prev[mg] = o;                 // for P3's cross-group read
        dout[(size_t)(b0 + mg) * OUT_ + s] = o;
      }
    }
    // no barrier: P1'/P2' touch only same-group rows; next cross-group
    // consumers (P3') are behind the P2'-end barrier.
  }
}

extern "C" void kernel_launch(void* const* d_in, const int* in_sizes, int n_in,
                              void* d_out, int out_size, void* d_ws, size_t ws_size,
                              hipStream_t stream) {
  (void)in_sizes; (void)n_in; (void)out_size; (void)ws_size;
  const float* x    = (const float*)d_in[0];
  const float* h0   = (const float*)d_in[1];
  const float* eWih = (const float*)d_in[2];
  const float* eWhh = (const float*)d_in[3];
  const float* ebih = (const float*)d_in[4];
  const float* ebhh = (const float*)d_in[5];
  const float* dWih = (const float*)d_in[6];
  const float* dWhh = (const float*)d_in[7];
  const float* dbih = (const float*)d_in[8];
  const float* dbhh = (const float*)d_in[9];
  const float* aWq  = (const float*)d_in[10];
  const float* abq  = (const float*)d_in[11];
  const float* f1W  = (const float*)d_in[12];
  const float* f1b  = (const float*)d_in[13];
  const float* f2W  = (const float*)d_in[14];
  const float* f2b  = (const float*)d_in[15];

  __hip_bfloat16* hs = (__hip_bfloat16*)d_ws;   // 134,217,728 B
  __hip_bfloat16* wb = (__hip_bfloat16*)((char*)d_ws + (size_t)B_ * T_ * H_ * 2);

  hipLaunchKernelGGL(af_convert_weights, dim3(256), dim3(256), 0, stream,
                     eWih, eWhh, dWhh, f1W, wb);
  hipLaunchKernelGGL(af_fused_kernel, dim3(NB_), dim3(NTH_), 0, stream,
                     x, h0, ebih, ebhh, dWih, dbih, dbhh, aWq, abq, f1b, f2W, f2b,
                     wb + PK_EIH_, wb + PK_EHH_, wb + PK_DHH_, wb + PK_F1_,
                     hs, (float*)d_out);
}